// Round 1
// baseline (1029.111 us; speedup 1.0000x reference)
//
#include <hip/hip_runtime.h>
#include <hip/hip_bf16.h>
#include <cstdint>

#define BATCH 65536
#define EXPERTS 8
#define IN_DIM 512
#define OUT_DIM 512

typedef short bf16x8 __attribute__((ext_vector_type(8)));
typedef float f32x4 __attribute__((ext_vector_type(4)));

__device__ __forceinline__ unsigned short f2bf_rne(float f) {
  unsigned u = __float_as_uint(f);
  u += 0x7FFFu + ((u >> 16) & 1u);   // round-to-nearest-even (inputs finite)
  return (unsigned short)(u >> 16);
}
__device__ __forceinline__ float bf2f(unsigned short h) {
  return __uint_as_float(((unsigned)h) << 16);
}

// async global->LDS, 16B per lane; lds base must be wave-uniform (guide §5)
__device__ __forceinline__ void async_copy16(void* lds, const void* g) {
  __builtin_amdgcn_global_load_lds((const __attribute__((address_space(1))) void*)g,
                                   (__attribute__((address_space(3))) void*)lds, 16, 0, 0);
}

// ---- prep 1: W [E][I][O] f32 -> Wt_hi/Wt_lo [E][O][I] bf16 (split + transpose) ----
__global__ __launch_bounds__(256) void wsplit_kernel(const float* __restrict__ W,
                                                     unsigned short* __restrict__ Wth,
                                                     unsigned short* __restrict__ Wtl) {
  __shared__ float t[32][33];
  const int e = blockIdx.z;
  const int i0 = blockIdx.x * 32;
  const int o0 = blockIdx.y * 32;
  const int tx = threadIdx.x & 31, ty = threadIdx.x >> 5;  // 32x8
#pragma unroll
  for (int p = 0; p < 4; ++p)
    t[ty + p * 8][tx] = W[(size_t)(e * IN_DIM + i0 + ty + p * 8) * OUT_DIM + o0 + tx];
  __syncthreads();
#pragma unroll
  for (int p = 0; p < 4; ++p) {
    float v = t[tx][ty + p * 8];                 // v = W[e][i0+tx][o0+ty+p*8]
    unsigned short hi = f2bf_rne(v);
    unsigned short lo = f2bf_rne(v - bf2f(hi));
    size_t idx = (size_t)(e * OUT_DIM + o0 + ty + p * 8) * IN_DIM + i0 + tx;
    Wth[idx] = hi;
    Wtl[idx] = lo;
  }
}

// ---- prep 2: x [B][I] f32 -> Xh/Xl bf16 ----
__global__ __launch_bounds__(256) void xsplit_kernel(const float* __restrict__ x,
                                                     unsigned short* __restrict__ Xh,
                                                     unsigned short* __restrict__ Xl) {
  const size_t i4 = (size_t)blockIdx.x * 256 + threadIdx.x;
  const float4 v = ((const float4*)x)[i4];
  ushort4 h, l;
  h.x = f2bf_rne(v.x); l.x = f2bf_rne(v.x - bf2f(h.x));
  h.y = f2bf_rne(v.y); l.y = f2bf_rne(v.y - bf2f(h.y));
  h.z = f2bf_rne(v.z); l.z = f2bf_rne(v.z - bf2f(h.z));
  h.w = f2bf_rne(v.w); l.w = f2bf_rne(v.w - bf2f(h.w));
  ((ushort4*)Xh)[i4] = h;
  ((ushort4*)Xl)[i4] = l;
}

// ---- main GEMM: 128x128 tile, BK=32, 4 waves (2x2), 16x16x32 bf16 MFMA x3 passes,
//      expert-outer loop with per-expert fp32 partial acc, gate+bias in epilogue ----
__global__ __launch_bounds__(256, 2) void moe_gemm_kernel(
    const unsigned short* __restrict__ Xh, const unsigned short* __restrict__ Xl,
    const unsigned short* __restrict__ Wth, const unsigned short* __restrict__ Wtl,
    const float* __restrict__ gates,   // [B][E]
    const float* __restrict__ bias,    // [E][O]
    float* __restrict__ out) {         // [B][O]
  __shared__ unsigned short sAh[128 * 32], sAl[128 * 32];
  __shared__ unsigned short sBh[128 * 32], sBl[128 * 32];
  __shared__ float sGate[128 * 8];
  __shared__ float sBias[EXPERTS * 128];

  const int tid = threadIdx.x;
  const int lane = tid & 63;
  const int wid = tid >> 6;
  const int wr = wid >> 1, wc = wid & 1;
  const int l15 = lane & 15, l4 = lane >> 4;

  const int bcol = blockIdx.x * 128;   // output-feature tile (4 tiles)
  const int brow = blockIdx.y * 128;   // batch tile (512 tiles)

  // one-time LDS: gates [128][8] and bias [8][128]
  {
    const int r = tid >> 1, q = (tid & 1) * 4;
    *(float4*)(sGate + r * 8 + q) =
        *(const float4*)(gates + (size_t)(brow + r) * EXPERTS + q);
    const int e = tid >> 5, c = (tid & 31) * 4;
    *(float4*)(sBias + e * 128 + c) =
        *(const float4*)(bias + (size_t)e * OUT_DIM + bcol + c);
  }

  // staging geometry: per call, thread t covers tile-row (call*64 + t/4), 16B chunk t%4
  const int srow = tid >> 2;            // 0..63
  const int schunk = (tid & 3) * 8;     // bf16-element offset within 32-wide k-slice
  const unsigned short* gAh = Xh + (size_t)(brow + srow) * IN_DIM + schunk;
  const unsigned short* gAl = Xl + (size_t)(brow + srow) * IN_DIM + schunk;

  f32x4 accY[4][4];
#pragma unroll
  for (int m = 0; m < 4; ++m)
#pragma unroll
    for (int n = 0; n < 4; ++n) accY[m][n] = (f32x4){0.f, 0.f, 0.f, 0.f};

  int aoff[4], boff[4];
#pragma unroll
  for (int m = 0; m < 4; ++m) aoff[m] = (wr * 64 + m * 16 + l15) * 32 + l4 * 8;
#pragma unroll
  for (int n = 0; n < 4; ++n) boff[n] = (wc * 64 + n * 16 + l15) * 32 + l4 * 8;

  const int wb = wid * 1024;  // per-wave LDS byte base within a 4KB half-tile

  for (int e = 0; e < EXPERTS; ++e) {
    const unsigned short* gBh = Wth + (size_t)(e * OUT_DIM + bcol + srow) * IN_DIM + schunk;
    const unsigned short* gBl = Wtl + (size_t)(e * OUT_DIM + bcol + srow) * IN_DIM + schunk;

    f32x4 accP[4][4];
#pragma unroll
    for (int m = 0; m < 4; ++m)
#pragma unroll
      for (int n = 0; n < 4; ++n) accP[m][n] = (f32x4){0.f, 0.f, 0.f, 0.f};

    for (int kk = 0; kk < IN_DIM; kk += 32) {
      async_copy16((char*)sAh + wb,        gAh + kk);
      async_copy16((char*)sAh + 4096 + wb, gAh + kk + 64 * IN_DIM);
      async_copy16((char*)sAl + wb,        gAl + kk);
      async_copy16((char*)sAl + 4096 + wb, gAl + kk + 64 * IN_DIM);
      async_copy16((char*)sBh + wb,        gBh + kk);
      async_copy16((char*)sBh + 4096 + wb, gBh + kk + 64 * IN_DIM);
      async_copy16((char*)sBl + wb,        gBl + kk);
      async_copy16((char*)sBl + 4096 + wb, gBl + kk + 64 * IN_DIM);
      __syncthreads();  // compiler drains vmcnt before s_barrier (guide §5)

      bf16x8 ah[4], al[4], bh[4], bl[4];
#pragma unroll
      for (int m = 0; m < 4; ++m) {
        ah[m] = *(const bf16x8*)(sAh + aoff[m]);
        al[m] = *(const bf16x8*)(sAl + aoff[m]);
      }
#pragma unroll
      for (int n = 0; n < 4; ++n) {
        bh[n] = *(const bf16x8*)(sBh + boff[n]);
        bl[n] = *(const bf16x8*)(sBl + boff[n]);
      }
#pragma unroll
      for (int m = 0; m < 4; ++m)
#pragma unroll
        for (int n = 0; n < 4; ++n) {
          accP[m][n] = __builtin_amdgcn_mfma_f32_16x16x32_bf16(ah[m], bh[n], accP[m][n], 0, 0, 0);
          accP[m][n] = __builtin_amdgcn_mfma_f32_16x16x32_bf16(al[m], bh[n], accP[m][n], 0, 0, 0);
          accP[m][n] = __builtin_amdgcn_mfma_f32_16x16x32_bf16(ah[m], bl[n], accP[m][n], 0, 0, 0);
        }
      __syncthreads();
    }

    // gate + bias: accY += g_row * (accP + b[e][col])
#pragma unroll
    for (int m = 0; m < 4; ++m) {
      float g[4];
#pragma unroll
      for (int j = 0; j < 4; ++j)
        g[j] = sGate[(wr * 64 + m * 16 + l4 * 4 + j) * 8 + e];
#pragma unroll
      for (int n = 0; n < 4; ++n) {
        const float bv = sBias[e * 128 + wc * 64 + n * 16 + l15];
#pragma unroll
        for (int j = 0; j < 4; ++j)
          accY[m][n][j] += g[j] * (accP[m][n][j] + bv);
      }
    }
  }

  // epilogue: C[row][col], row = brow+wr*64+m*16+l4*4+j, col = bcol+wc*64+n*16+l15
#pragma unroll
  for (int m = 0; m < 4; ++m)
#pragma unroll
    for (int n = 0; n < 4; ++n) {
      const int row = brow + wr * 64 + m * 16 + l4 * 4;
      const int col = bcol + wc * 64 + n * 16 + l15;
#pragma unroll
      for (int j = 0; j < 4; ++j)
        out[(size_t)(row + j) * OUT_DIM + col] = accY[m][n][j];
    }
}

extern "C" void kernel_launch(void* const* d_in, const int* in_sizes, int n_in,
                              void* d_out, int out_size, void* d_ws, size_t ws_size,
                              hipStream_t stream) {
  const float* x     = (const float*)d_in[0];  // [B][I]
  const float* gates = (const float*)d_in[1];  // [B][E]
  const float* W     = (const float*)d_in[2];  // [E][I][O]
  const float* bias  = (const float*)d_in[3];  // [E][1][O]
  float* out = (float*)d_out;

  // workspace layout: Wt_hi(4MiB) | Wt_lo(4MiB) | Xh(64MiB) | Xl(64MiB) = 136MiB
  unsigned short* Wth = (unsigned short*)d_ws;
  unsigned short* Wtl = Wth + (size_t)EXPERTS * IN_DIM * OUT_DIM;
  unsigned short* Xh  = Wtl + (size_t)EXPERTS * IN_DIM * OUT_DIM;
  unsigned short* Xl  = Xh + (size_t)BATCH * IN_DIM;

  wsplit_kernel<<<dim3(16, 16, 8), 256, 0, stream>>>(W, Wth, Wtl);
  xsplit_kernel<<<dim3(BATCH * IN_DIM / 4 / 256), 256, 0, stream>>>(x, Xh, Xl);
  moe_gemm_kernel<<<dim3(OUT_DIM / 128, BATCH / 128), 256, 0, stream>>>(
      Xh, Xl, Wth, Wtl, gates, bias, out);
}